// Round 4
// baseline (262.597 us; speedup 1.0000x reference)
//
#include <hip/hip_runtime.h>
#include <stdint.h>

#define BB 2
#define TT 2048
#define EE 1024
#define HH 16
#define DD 64
#define MM (BB*TT)   // 4096 rows

typedef unsigned short u16;
typedef __attribute__((ext_vector_type(4))) float f32x4;
typedef __attribute__((ext_vector_type(8))) __bf16 bf16x8;
typedef __attribute__((ext_vector_type(8))) u16 u16x8;

union FragU { u16x8 u; bf16x8 b; };

__device__ __forceinline__ u16 f2bf(float f) {
  uint32_t u = __float_as_uint(f);
  u += 0x7fffu + ((u >> 16) & 1u);   // RNE (inputs are finite)
  return (u16)(u >> 16);
}

// ---------------- f32 -> bf16 convert (8 elems/thread) ----------------
__global__ __launch_bounds__(256) void cvt_f32_bf16(const float* __restrict__ src,
                                                    u16* __restrict__ dst, int n8) {
  int i = blockIdx.x * 256 + threadIdx.x;
  if (i >= n8) return;
  const f32x4* s4 = (const f32x4*)src;
  f32x4 a = s4[2*i], b = s4[2*i+1];
  u16x8 o;
  o[0]=f2bf(a[0]); o[1]=f2bf(a[1]); o[2]=f2bf(a[2]); o[3]=f2bf(a[3]);
  o[4]=f2bf(b[0]); o[5]=f2bf(b[1]); o[6]=f2bf(b[2]); o[7]=f2bf(b[3]);
  ((u16x8*)dst)[i] = o;
}

// ---------------- weight transpose + convert: Wt[n][k] = bf16(W[k][n]) ----------------
__global__ __launch_bounds__(256) void wt_cvt4(const float* __restrict__ W0, const float* __restrict__ W1,
                                               const float* __restrict__ W2, const float* __restrict__ W3,
                                               u16* __restrict__ T0, u16* __restrict__ T1,
                                               u16* __restrict__ T2, u16* __restrict__ T3) {
  const float* W; u16* Tp;
  switch (blockIdx.z) {
    case 0: W = W0; Tp = T0; break;
    case 1: W = W1; Tp = T1; break;
    case 2: W = W2; Tp = T2; break;
    default: W = W3; Tp = T3; break;
  }
  int n0 = blockIdx.x * 64, k0 = blockIdx.y * 64;
  __shared__ alignas(16) float tile[64][65];
  int t = threadIdx.x;
#pragma unroll
  for (int i = 0; i < 16; ++i) {
    int idx = i*256 + t; int r = idx >> 6, c = idx & 63;
    tile[r][c] = W[(size_t)(k0 + r) * EE + n0 + c];
  }
  __syncthreads();
#pragma unroll
  for (int i = 0; i < 16; ++i) {
    int idx = i*256 + t; int rn = idx >> 6, ck = idx & 63;
    Tp[(size_t)(n0 + rn) * EE + k0 + ck] = f2bf(tile[ck][rn]);
  }
}

// ---------------- GEMM: C[M][N] = A[M][K] @ Bt[N][K]^T + bias[N] ----------------
// 128x128 tile, BK=64, 4 waves (2x2 quadrants), 16x16x32 bf16 MFMA.
// Padded LDS (row stride 72 u16 = 144 B). F32OUT selects output dtype.
template <bool F32OUT>
__global__ __launch_bounds__(256) void gemm_bt(const u16* __restrict__ A, const u16* __restrict__ Bt,
                                               const float* __restrict__ bias, void* __restrict__ Cout,
                                               int M, int N, int K) {
  __shared__ alignas(16) u16 As[128][72];
  __shared__ alignas(16) u16 Bs[128][72];
  const int t = threadIdx.x;
  const int lane = t & 63, wave = t >> 6;
  const int wr = wave >> 1, wc = wave & 1;
  const int bm = blockIdx.y, bn = blockIdx.x;

  f32x4 acc[4][4] = {};

  const int srow = t >> 3;            // 0..31
  const int scol = (t & 7) * 8;       // u16 col 0..56
  const u16* Ag = A + (size_t)(bm * 128) * K;
  const u16* Bg = Bt + (size_t)(bn * 128) * K;

  const int nk = K / 64;
  for (int kt = 0; kt < nk; ++kt) {
    const int k0 = kt * 64;
    __syncthreads();
#pragma unroll
    for (int r = 0; r < 4; ++r) {
      int row = r*32 + srow;
      *(u16x8*)&As[row][scol] = *(const u16x8*)(Ag + (size_t)row * K + k0 + scol);
      *(u16x8*)&Bs[row][scol] = *(const u16x8*)(Bg + (size_t)row * K + k0 + scol);
    }
    __syncthreads();
#pragma unroll
    for (int ks = 0; ks < 2; ++ks) {
      const int kc = ks*32 + ((lane >> 4) << 3);
      FragU af[4], bfr[4];
#pragma unroll
      for (int mi = 0; mi < 4; ++mi)
        af[mi].u = *(const u16x8*)&As[wr*64 + mi*16 + (lane & 15)][kc];
#pragma unroll
      for (int nj = 0; nj < 4; ++nj)
        bfr[nj].u = *(const u16x8*)&Bs[wc*64 + nj*16 + (lane & 15)][kc];
#pragma unroll
      for (int mi = 0; mi < 4; ++mi)
#pragma unroll
        for (int nj = 0; nj < 4; ++nj)
          acc[mi][nj] = __builtin_amdgcn_mfma_f32_16x16x32_bf16(af[mi].b, bfr[nj].b, acc[mi][nj], 0, 0, 0);
    }
  }

  // epilogue: bias + store. C/D layout: col=lane&15, row=(lane>>4)*4+reg
  const int cbase = bn*128 + wc*64 + (lane & 15);
  float bv[4];
#pragma unroll
  for (int nj = 0; nj < 4; ++nj) bv[nj] = bias[cbase + nj*16];
#pragma unroll
  for (int mi = 0; mi < 4; ++mi) {
    int row0 = bm*128 + wr*64 + mi*16 + ((lane >> 4) << 2);
#pragma unroll
    for (int i = 0; i < 4; ++i) {
      if (F32OUT) {
        float* Cp = (float*)Cout + (size_t)(row0 + i) * N + cbase;
#pragma unroll
        for (int nj = 0; nj < 4; ++nj)
          Cp[nj*16] = acc[mi][nj][i] + bv[nj];
      } else {
        u16* Cp = (u16*)Cout + (size_t)(row0 + i) * N + cbase;
#pragma unroll
        for (int nj = 0; nj < 4; ++nj)
          Cp[nj*16] = f2bf(acc[mi][nj][i] + bv[nj]);
      }
    }
  }
}

// ---------------- V transpose: V[b][t][h][d] -> Vt[b][h][d][t] ----------------
__global__ __launch_bounds__(256) void transpose_v(const u16* __restrict__ V, u16* __restrict__ Vt) {
  int tb = blockIdx.x, h = blockIdx.y, b = blockIdx.z;
  __shared__ alignas(16) u16 tile[64][66];
  int t = threadIdx.x;
  int t0 = tb * 64;
#pragma unroll
  for (int i = 0; i < 16; ++i) {
    int idx = i*256 + t; int r = idx >> 6, c = idx & 63;
    tile[r][c] = V[(size_t)(b*TT + t0 + r) * EE + h*DD + c];
  }
  __syncthreads();
#pragma unroll
  for (int i = 0; i < 16; ++i) {
    int idx = i*256 + t; int dd = idx >> 6, tt2 = idx & 63;
    Vt[((size_t)(b*HH + h) * DD + dd) * TT + t0 + tt2] = tile[tt2][dd];
  }
}

// ---------------- causal flash attention (MFMA) ----------------
// Block: (qt, h, b), 256 threads = 4 waves; wave w owns q-rows [qt*128+w*32, +32).
// K tile [64 kv][64 d] and Vt tile [64 d][64 kv] staged in padded LDS per kv-block.
__global__ __launch_bounds__(256) void attn(const u16* __restrict__ Q, const u16* __restrict__ K,
                                            const u16* __restrict__ Vt, u16* __restrict__ O) {
  const int qt = blockIdx.x, h = blockIdx.y, b = blockIdx.z;
  const int t = threadIdx.x, lane = t & 63, w = t >> 6;
  __shared__ alignas(16) u16 Ks[64][72];
  __shared__ alignas(16) u16 Vs[64][72];
  __shared__ alignas(16) u16 Ps[4][32][72];   // wave-private P tiles

  const int q0 = qt * 128;
  const int qw0 = q0 + w * 32;

  // hoist Q fragments: rows qw0 + qi*16 + (lane&15), d = ks*32 + (lane>>4)*8 + 0..7
  FragU qf[2][2];
  const u16* Qbase = Q + ((size_t)(b*TT) + qw0) * EE + h*DD;
#pragma unroll
  for (int qi = 0; qi < 2; ++qi)
#pragma unroll
    for (int ks = 0; ks < 2; ++ks) {
      int row = qi*16 + (lane & 15);
      int col = ks*32 + ((lane >> 4) << 3);
      qf[qi][ks].u = *(const u16x8*)(Qbase + (size_t)row * EE + col);
    }

  f32x4 oacc[2][4] = {};
  float m_run[2][4], l_run[2][4];
#pragma unroll
  for (int qi = 0; qi < 2; ++qi)
#pragma unroll
    for (int i = 0; i < 4; ++i) { m_run[qi][i] = -1e30f; l_run[qi][i] = 0.f; }

  const u16* Kbase = K + (size_t)(b*TT) * EE + h*DD;
  const u16* Vtbase = Vt + (size_t)(b*HH + h) * DD * TT;

  const int srow = t >> 3;          // 0..31
  const int scol = (t & 7) * 8;     // u16 col

  const float c1 = 0.125f * 1.44269504088896340736f;  // scale * log2(e)

  const int nkv = 2*qt + 2;
  for (int j = 0; j < nkv; ++j) {
    const int kv0 = j * 64;
    __syncthreads();
    // stage K tile [kv][d] and V^T tile [d][kv]
#pragma unroll
    for (int r = 0; r < 2; ++r) {
      int row = r*32 + srow;
      *(u16x8*)&Ks[row][scol] = *(const u16x8*)(Kbase + (size_t)(kv0 + row) * EE + scol);
      *(u16x8*)&Vs[row][scol] = *(const u16x8*)(Vtbase + (size_t)row * TT + kv0 + scol);
    }
    __syncthreads();
    if (kv0 > qw0 + 31) continue;   // wave has no unmasked cols in this block

    // S = Q K^T  (S frag [qi][nj]: rows qw0+qi*16+(l>>4)*4+reg, cols kv0+nj*16+(l&15))
    f32x4 s[2][4] = {};
#pragma unroll
    for (int ks = 0; ks < 2; ++ks) {
      const int kc = ks*32 + ((lane >> 4) << 3);
      FragU kf[4];
#pragma unroll
      for (int nj = 0; nj < 4; ++nj)
        kf[nj].u = *(const u16x8*)&Ks[nj*16 + (lane & 15)][kc];
#pragma unroll
      for (int qi = 0; qi < 2; ++qi)
#pragma unroll
        for (int nj = 0; nj < 4; ++nj)
          s[qi][nj] = __builtin_amdgcn_mfma_f32_16x16x32_bf16(qf[qi][ks].b, kf[nj].b, s[qi][nj], 0, 0, 0);
    }

    const bool full = (kv0 + 63 <= qw0);  // entire tile unmasked for all rows of this wave
#pragma unroll
    for (int qi = 0; qi < 2; ++qi) {
#pragma unroll
      for (int i = 0; i < 4; ++i) {
        int row = qw0 + qi*16 + ((lane >> 4) << 2) + i;
        float tv[4];
#pragma unroll
        for (int nj = 0; nj < 4; ++nj) {
          float xv = s[qi][nj][i] * c1;
          if (!full) {
            int col = kv0 + nj*16 + (lane & 15);
            if (col > row) xv = -1e30f;
          }
          tv[nj] = xv;
        }
        float mx = fmaxf(fmaxf(tv[0], tv[1]), fmaxf(tv[2], tv[3]));
        mx = fmaxf(mx, __shfl_xor(mx, 1));
        mx = fmaxf(mx, __shfl_xor(mx, 2));
        mx = fmaxf(mx, __shfl_xor(mx, 4));
        mx = fmaxf(mx, __shfl_xor(mx, 8));
        float mo = m_run[qi][i];
        float mn = fmaxf(mo, mx);
        float f = exp2f(mo - mn);
        float ssum = 0.f;
        u16 pb[4];
#pragma unroll
        for (int nj = 0; nj < 4; ++nj) {
          float p = exp2f(tv[nj] - mn);
          ssum += p;
          pb[nj] = f2bf(p);
        }
        ssum += __shfl_xor(ssum, 1);
        ssum += __shfl_xor(ssum, 2);
        ssum += __shfl_xor(ssum, 4);
        ssum += __shfl_xor(ssum, 8);
        m_run[qi][i] = mn;
        l_run[qi][i] = l_run[qi][i] * f + ssum;
#pragma unroll
        for (int dj = 0; dj < 4; ++dj) oacc[qi][dj][i] *= f;
        int prow = qi*16 + ((lane >> 4) << 2) + i;
#pragma unroll
        for (int nj = 0; nj < 4; ++nj)
          Ps[w][prow][nj*16 + (lane & 15)] = pb[nj];
      }
    }

    // O += P @ V   (A = P from Ps, B = V via Vs = V^T tile)
#pragma unroll
    for (int ks = 0; ks < 2; ++ks) {
      const int kc = ks*32 + ((lane >> 4) << 3);
      FragU pf[2], vf[4];
#pragma unroll
      for (int qi = 0; qi < 2; ++qi)
        pf[qi].u = *(const u16x8*)&Ps[w][qi*16 + (lane & 15)][kc];
#pragma unroll
      for (int dj = 0; dj < 4; ++dj)
        vf[dj].u = *(const u16x8*)&Vs[dj*16 + (lane & 15)][kc];
#pragma unroll
      for (int qi = 0; qi < 2; ++qi)
#pragma unroll
        for (int dj = 0; dj < 4; ++dj)
          oacc[qi][dj] = __builtin_amdgcn_mfma_f32_16x16x32_bf16(pf[qi].b, vf[dj].b, oacc[qi][dj], 0, 0, 0);
    }
  }

  // finalize: O /= l, store bf16
  u16* Ob = O + ((size_t)(b*TT) + qw0) * EE + h*DD;
#pragma unroll
  for (int qi = 0; qi < 2; ++qi)
#pragma unroll
    for (int i = 0; i < 4; ++i) {
      float inv = 1.f / l_run[qi][i];
      int row = qi*16 + ((lane >> 4) << 2) + i;
#pragma unroll
      for (int dj = 0; dj < 4; ++dj)
        Ob[(size_t)row * EE + dj*16 + (lane & 15)] = f2bf(oacc[qi][dj][i] * inv);
    }
}

// ---------------- launch ----------------
extern "C" void kernel_launch(void* const* d_in, const int* in_sizes, int n_in,
                              void* d_out, int out_size, void* d_ws, size_t ws_size,
                              hipStream_t stream) {
  const float* x  = (const float*)d_in[0];
  const float* y  = (const float*)d_in[1];
  // d_in[2] = mask (tril causal; implemented analytically)
  const float* Wq = (const float*)d_in[3];
  const float* bq = (const float*)d_in[4];
  const float* Wk = (const float*)d_in[5];
  const float* bk = (const float*)d_in[6];
  const float* Wv = (const float*)d_in[7];
  const float* bv = (const float*)d_in[8];
  const float* Wo = (const float*)d_in[9];
  const float* bo = (const float*)d_in[10];

  if (ws_size < (size_t)67108864) return;  // need 64 MiB scratch

  char* ws = (char*)d_ws;
  u16* xb  = (u16*)(ws + 0);
  u16* yb  = (u16*)(ws + 8388608);
  u16* Wqt = (u16*)(ws + 16777216);
  u16* Wkt = (u16*)(ws + 18874368);
  u16* Wvt = (u16*)(ws + 20971520);
  u16* Wot = (u16*)(ws + 23068672);
  u16* Qb  = (u16*)(ws + 25165824);
  u16* Kb  = (u16*)(ws + 33554432);
  u16* Vb  = (u16*)(ws + 41943040);
  u16* Vtb = (u16*)(ws + 50331648);
  u16* Atb = (u16*)(ws + 58720256);

  cvt_f32_bf16<<<2048, 256, 0, stream>>>(x, xb, MM*EE/8);
  cvt_f32_bf16<<<2048, 256, 0, stream>>>(y, yb, MM*EE/8);
  wt_cvt4<<<dim3(16,16,4), 256, 0, stream>>>(Wq, Wk, Wv, Wo, Wqt, Wkt, Wvt, Wot);
  gemm_bt<false><<<dim3(8,32), 256, 0, stream>>>(xb, Wqt, bq, Qb, MM, EE, EE);
  gemm_bt<false><<<dim3(8,32), 256, 0, stream>>>(yb, Wkt, bk, Kb, MM, EE, EE);
  gemm_bt<false><<<dim3(8,32), 256, 0, stream>>>(yb, Wvt, bv, Vb, MM, EE, EE);
  transpose_v<<<dim3(32,16,2), 256, 0, stream>>>(Vb, Vtb);
  attn<<<dim3(16,16,2), 256, 0, stream>>>(Qb, Kb, Vtb, Atb);
  gemm_bt<true><<<dim3(8,32), 256, 0, stream>>>(Atb, Wot, bo, d_out, MM, EE, EE);
}

// Round 5
// 163.497 us; speedup vs baseline: 1.6061x; 1.6061x over previous
//
#include <hip/hip_runtime.h>
#include <stdint.h>

#define BB 2
#define TT 2048
#define EE 1024
#define HH 16
#define DD 64
#define MM (BB*TT)   // 4096 rows

typedef unsigned short u16;
typedef __attribute__((ext_vector_type(4))) float f32x4;
typedef __attribute__((ext_vector_type(8))) __bf16 bf16x8;
typedef __attribute__((ext_vector_type(8))) u16 u16x8;

union FragU { u16x8 u; bf16x8 b; };

__device__ __forceinline__ u16 f2bf(float f) {
  uint32_t u = __float_as_uint(f);
  u += 0x7fffu + ((u >> 16) & 1u);   // RNE (inputs are finite)
  return (u16)(u >> 16);
}

// ---------------- f32 -> bf16 convert (8 elems/thread) ----------------
__global__ __launch_bounds__(256) void cvt_f32_bf16(const float* __restrict__ src,
                                                    u16* __restrict__ dst, int n8) {
  int i = blockIdx.x * 256 + threadIdx.x;
  if (i >= n8) return;
  const f32x4* s4 = (const f32x4*)src;
  f32x4 a = s4[2*i], b = s4[2*i+1];
  u16x8 o;
  o[0]=f2bf(a[0]); o[1]=f2bf(a[1]); o[2]=f2bf(a[2]); o[3]=f2bf(a[3]);
  o[4]=f2bf(b[0]); o[5]=f2bf(b[1]); o[6]=f2bf(b[2]); o[7]=f2bf(b[3]);
  ((u16x8*)dst)[i] = o;
}

// ---------------- weight transpose + convert: Wt[n][k] = bf16(W[k][n]) ----------------
__global__ __launch_bounds__(256) void wt_cvt4(const float* __restrict__ W0, const float* __restrict__ W1,
                                               const float* __restrict__ W2, const float* __restrict__ W3,
                                               u16* __restrict__ T0, u16* __restrict__ T1,
                                               u16* __restrict__ T2, u16* __restrict__ T3) {
  const float* W; u16* Tp;
  switch (blockIdx.z) {
    case 0: W = W0; Tp = T0; break;
    case 1: W = W1; Tp = T1; break;
    case 2: W = W2; Tp = T2; break;
    default: W = W3; Tp = T3; break;
  }
  int n0 = blockIdx.x * 64, k0 = blockIdx.y * 64;
  __shared__ alignas(16) float tile[64][65];
  int t = threadIdx.x;
#pragma unroll
  for (int i = 0; i < 16; ++i) {
    int idx = i*256 + t; int r = idx >> 6, c = idx & 63;
    tile[r][c] = W[(size_t)(k0 + r) * EE + n0 + c];
  }
  __syncthreads();
#pragma unroll
  for (int i = 0; i < 16; ++i) {
    int idx = i*256 + t; int rn = idx >> 6, ck = idx & 63;
    Tp[(size_t)(n0 + rn) * EE + k0 + ck] = f2bf(tile[ck][rn]);
  }
}

// ---------------- GEMM: C[M][N] = A[M][K] @ Bt[N][K]^T + bias[N] ----------------
// 64x128 tile, BK=64, 4 waves (2x2: 32-row x 64-col quadrants), 16x16x32 bf16 MFMA.
// Grid = (N/128, M/64) = 512 blocks -> 2 blocks/CU. Register-prefetch staging.
template <bool F32OUT>
__global__ __launch_bounds__(256) void gemm_bt(const u16* __restrict__ A, const u16* __restrict__ Bt,
                                               const float* __restrict__ bias, void* __restrict__ Cout,
                                               int M, int N, int K) {
  __shared__ alignas(16) u16 As[64][72];
  __shared__ alignas(16) u16 Bs[128][72];
  const int t = threadIdx.x;
  const int lane = t & 63, wave = t >> 6;
  const int wr = wave >> 1, wc = wave & 1;
  const int bm = blockIdx.y, bn = blockIdx.x;

  f32x4 acc[2][4] = {};

  const int srow = t >> 3;            // 0..31
  const int scol = (t & 7) * 8;       // u16 col 0..56
  const u16* Ag = A + (size_t)(bm * 64) * K;
  const u16* Bg = Bt + (size_t)(bn * 128) * K;

  u16x8 ra[2], rb[4];
#pragma unroll
  for (int r = 0; r < 2; ++r)
    ra[r] = *(const u16x8*)(Ag + (size_t)(r*32 + srow) * K + scol);
#pragma unroll
  for (int r = 0; r < 4; ++r)
    rb[r] = *(const u16x8*)(Bg + (size_t)(r*32 + srow) * K + scol);

  const int nk = K / 64;
  for (int kt = 0; kt < nk; ++kt) {
    __syncthreads();
#pragma unroll
    for (int r = 0; r < 2; ++r) *(u16x8*)&As[r*32 + srow][scol] = ra[r];
#pragma unroll
    for (int r = 0; r < 4; ++r) *(u16x8*)&Bs[r*32 + srow][scol] = rb[r];
    __syncthreads();
    if (kt + 1 < nk) {
      const int k0 = (kt + 1) * 64;
#pragma unroll
      for (int r = 0; r < 2; ++r)
        ra[r] = *(const u16x8*)(Ag + (size_t)(r*32 + srow) * K + k0 + scol);
#pragma unroll
      for (int r = 0; r < 4; ++r)
        rb[r] = *(const u16x8*)(Bg + (size_t)(r*32 + srow) * K + k0 + scol);
    }
#pragma unroll
    for (int ks = 0; ks < 2; ++ks) {
      const int kc = ks*32 + ((lane >> 4) << 3);
      FragU af[2], bfr[4];
#pragma unroll
      for (int mi = 0; mi < 2; ++mi)
        af[mi].u = *(const u16x8*)&As[wr*32 + mi*16 + (lane & 15)][kc];
#pragma unroll
      for (int nj = 0; nj < 4; ++nj)
        bfr[nj].u = *(const u16x8*)&Bs[wc*64 + nj*16 + (lane & 15)][kc];
#pragma unroll
      for (int mi = 0; mi < 2; ++mi)
#pragma unroll
        for (int nj = 0; nj < 4; ++nj)
          acc[mi][nj] = __builtin_amdgcn_mfma_f32_16x16x32_bf16(af[mi].b, bfr[nj].b, acc[mi][nj], 0, 0, 0);
    }
  }

  // epilogue: bias + store. C/D layout: col=lane&15, row=(lane>>4)*4+reg
  const int cbase = bn*128 + wc*64 + (lane & 15);
  float bv[4];
#pragma unroll
  for (int nj = 0; nj < 4; ++nj) bv[nj] = bias[cbase + nj*16];
#pragma unroll
  for (int mi = 0; mi < 2; ++mi) {
    int row0 = bm*64 + wr*32 + mi*16 + ((lane >> 4) << 2);
#pragma unroll
    for (int i = 0; i < 4; ++i) {
      if (F32OUT) {
        float* Cp = (float*)Cout + (size_t)(row0 + i) * N + cbase;
#pragma unroll
        for (int nj = 0; nj < 4; ++nj)
          Cp[nj*16] = acc[mi][nj][i] + bv[nj];
      } else {
        u16* Cp = (u16*)Cout + (size_t)(row0 + i) * N + cbase;
#pragma unroll
        for (int nj = 0; nj < 4; ++nj)
          Cp[nj*16] = f2bf(acc[mi][nj][i] + bv[nj]);
      }
    }
  }
}

// ---------------- V transpose: V[b][t][h][d] -> Vt[b][h][d][t] ----------------
__global__ __launch_bounds__(256) void transpose_v(const u16* __restrict__ V, u16* __restrict__ Vt) {
  int tb = blockIdx.x, h = blockIdx.y, b = blockIdx.z;
  __shared__ alignas(16) u16 tile[64][66];
  int t = threadIdx.x;
  int t0 = tb * 64;
#pragma unroll
  for (int i = 0; i < 16; ++i) {
    int idx = i*256 + t; int r = idx >> 6, c = idx & 63;
    tile[r][c] = V[(size_t)(b*TT + t0 + r) * EE + h*DD + c];
  }
  __syncthreads();
#pragma unroll
  for (int i = 0; i < 16; ++i) {
    int idx = i*256 + t; int dd = idx >> 6, tt2 = idx & 63;
    Vt[((size_t)(b*HH + h) * DD + dd) * TT + t0 + tt2] = tile[tt2][dd];
  }
}

// ---------------- causal flash attention (MFMA, 8 waves x 16 q-rows) ----------------
// Flat grid of 512 blocks; block i<256 -> (qt=i&15, h=i>>4, b=0),
// block i>=256 -> (qt=15-(j&15), h=j>>4, b=1) with j=i-256 — pairs long+short
// blocks on the same CU under round-robin dispatch (34 kv-tiles per pair).
__global__ __launch_bounds__(512) void attn(const u16* __restrict__ Q, const u16* __restrict__ K,
                                            const u16* __restrict__ Vt, u16* __restrict__ O) {
  const int bi = blockIdx.x;
  const int phase = bi >> 8, j8 = bi & 255;
  const int qt = phase ? 15 - (j8 & 15) : (j8 & 15);
  const int h = j8 >> 4;
  const int b = phase;

  const int t = threadIdx.x, lane = t & 63, w = t >> 6;
  __shared__ alignas(16) u16 Ks[64][72];
  __shared__ alignas(16) u16 Vs[64][72];
  __shared__ alignas(16) u16 Ps[8][16][72];   // wave-private P tiles

  const int q0 = qt * 128;
  const int qw0 = q0 + w * 16;                // 16 q-rows per wave

  // hoist Q fragments: rows qw0 + (lane&15), d = ks*32 + (lane>>4)*8 + 0..7
  FragU qf[2];
  const u16* Qbase = Q + ((size_t)(b*TT) + qw0) * EE + h*DD;
#pragma unroll
  for (int ks = 0; ks < 2; ++ks) {
    int col = ks*32 + ((lane >> 4) << 3);
    qf[ks].u = *(const u16x8*)(Qbase + (size_t)(lane & 15) * EE + col);
  }

  f32x4 oacc[4] = {};
  float m_run[4], l_run[4];
#pragma unroll
  for (int i = 0; i < 4; ++i) { m_run[i] = -1e30f; l_run[i] = 0.f; }

  const u16* Kbase = K + (size_t)(b*TT) * EE + h*DD;
  const u16* Vtbase = Vt + (size_t)(b*HH + h) * DD * TT;

  // staging: 512 threads, one u16x8 each for K and V^T tiles
  const int srow = t >> 3;          // 0..63
  const int scol = (t & 7) * 8;     // u16 col

  const float c1 = 0.125f * 1.44269504088896340736f;  // scale * log2(e)

  const int nkv = 2*qt + 2;
  // prefetch tile 0
  u16x8 rk = *(const u16x8*)(Kbase + (size_t)srow * EE + scol);
  u16x8 rv = *(const u16x8*)(Vtbase + (size_t)srow * TT + scol);

  for (int j = 0; j < nkv; ++j) {
    const int kv0 = j * 64;
    __syncthreads();
    *(u16x8*)&Ks[srow][scol] = rk;
    *(u16x8*)&Vs[srow][scol] = rv;
    __syncthreads();
    if (j + 1 < nkv) {
      const int kv1 = kv0 + 64;
      rk = *(const u16x8*)(Kbase + (size_t)(kv1 + srow) * EE + scol);
      rv = *(const u16x8*)(Vtbase + (size_t)srow * TT + kv1 + scol);
    }
    if (kv0 > qw0 + 15) continue;   // wave fully masked in this tile (barriers already done)

    // S = Q K^T  (S frag: row q = qw0+(lane>>4)*4+i, col kv = kv0+nj*16+(lane&15))
    f32x4 s[4] = {};
#pragma unroll
    for (int ks = 0; ks < 2; ++ks) {
      const int kc = ks*32 + ((lane >> 4) << 3);
      FragU kf[4];
#pragma unroll
      for (int nj = 0; nj < 4; ++nj)
        kf[nj].u = *(const u16x8*)&Ks[nj*16 + (lane & 15)][kc];
#pragma unroll
      for (int nj = 0; nj < 4; ++nj)
        s[nj] = __builtin_amdgcn_mfma_f32_16x16x32_bf16(qf[ks].b, kf[nj].b, s[nj], 0, 0, 0);
    }

    const bool full = (kv0 + 63 <= qw0);  // entire tile unmasked for all rows of this wave
#pragma unroll
    for (int i = 0; i < 4; ++i) {
      int row = qw0 + ((lane >> 4) << 2) + i;
      float tv[4];
#pragma unroll
      for (int nj = 0; nj < 4; ++nj) {
        float xv = s[nj][i] * c1;
        if (!full) {
          int col = kv0 + nj*16 + (lane & 15);
          if (col > row) xv = -1e30f;
        }
        tv[nj] = xv;
      }
      float mx = fmaxf(fmaxf(tv[0], tv[1]), fmaxf(tv[2], tv[3]));
      mx = fmaxf(mx, __shfl_xor(mx, 1));
      mx = fmaxf(mx, __shfl_xor(mx, 2));
      mx = fmaxf(mx, __shfl_xor(mx, 4));
      mx = fmaxf(mx, __shfl_xor(mx, 8));
      float mo = m_run[i];
      float mn = fmaxf(mo, mx);
      float f = exp2f(mo - mn);
      float ssum = 0.f;
      u16 pb[4];
#pragma unroll
      for (int nj = 0; nj < 4; ++nj) {
        float p = exp2f(tv[nj] - mn);
        ssum += p;
        pb[nj] = f2bf(p);
      }
      ssum += __shfl_xor(ssum, 1);
      ssum += __shfl_xor(ssum, 2);
      ssum += __shfl_xor(ssum, 4);
      ssum += __shfl_xor(ssum, 8);
      m_run[i] = mn;
      l_run[i] = l_run[i] * f + ssum;
#pragma unroll
      for (int dj = 0; dj < 4; ++dj) oacc[dj][i] *= f;
      int prow = ((lane >> 4) << 2) + i;
#pragma unroll
      for (int nj = 0; nj < 4; ++nj)
        Ps[w][prow][nj*16 + (lane & 15)] = pb[nj];
    }

    // O += P @ V   (A = P from Ps, B = V via Vs = V^T tile)
#pragma unroll
    for (int ks = 0; ks < 2; ++ks) {
      const int kc = ks*32 + ((lane >> 4) << 3);
      FragU pf, vf[4];
      pf.u = *(const u16x8*)&Ps[w][lane & 15][kc];
#pragma unroll
      for (int dj = 0; dj < 4; ++dj)
        vf[dj].u = *(const u16x8*)&Vs[dj*16 + (lane & 15)][kc];
#pragma unroll
      for (int dj = 0; dj < 4; ++dj)
        oacc[dj] = __builtin_amdgcn_mfma_f32_16x16x32_bf16(pf.b, vf[dj].b, oacc[dj], 0, 0, 0);
    }
  }

  // finalize: O /= l, store bf16
  u16* Ob = O + ((size_t)(b*TT) + qw0) * EE + h*DD;
#pragma unroll
  for (int i = 0; i < 4; ++i) {
    float inv = 1.f / l_run[i];
    int row = ((lane >> 4) << 2) + i;
#pragma unroll
    for (int dj = 0; dj < 4; ++dj)
      Ob[(size_t)row * EE + dj*16 + (lane & 15)] = f2bf(oacc[dj][i] * inv);
  }
}

// ---------------- launch ----------------
extern "C" void kernel_launch(void* const* d_in, const int* in_sizes, int n_in,
                              void* d_out, int out_size, void* d_ws, size_t ws_size,
                              hipStream_t stream) {
  const float* x  = (const float*)d_in[0];
  const float* y  = (const float*)d_in[1];
  // d_in[2] = mask (tril causal; implemented analytically)
  const float* Wq = (const float*)d_in[3];
  const float* bq = (const float*)d_in[4];
  const float* Wk = (const float*)d_in[5];
  const float* bk = (const float*)d_in[6];
  const float* Wv = (const float*)d_in[7];
  const float* bv = (const float*)d_in[8];
  const float* Wo = (const float*)d_in[9];
  const float* bo = (const float*)d_in[10];

  if (ws_size < (size_t)67108864) return;  // need 64 MiB scratch

  char* ws = (char*)d_ws;
  u16* xb  = (u16*)(ws + 0);
  u16* yb  = (u16*)(ws + 8388608);
  u16* Wqt = (u16*)(ws + 16777216);
  u16* Wkt = (u16*)(ws + 18874368);
  u16* Wvt = (u16*)(ws + 20971520);
  u16* Wot = (u16*)(ws + 23068672);
  u16* Qb  = (u16*)(ws + 25165824);
  u16* Kb  = (u16*)(ws + 33554432);
  u16* Vb  = (u16*)(ws + 41943040);
  u16* Vtb = (u16*)(ws + 50331648);
  u16* Atb = (u16*)(ws + 58720256);

  cvt_f32_bf16<<<2048, 256, 0, stream>>>(x, xb, MM*EE/8);
  cvt_f32_bf16<<<2048, 256, 0, stream>>>(y, yb, MM*EE/8);
  wt_cvt4<<<dim3(16,16,4), 256, 0, stream>>>(Wq, Wk, Wv, Wo, Wqt, Wkt, Wvt, Wot);
  gemm_bt<false><<<dim3(8,64), 256, 0, stream>>>(xb, Wqt, bq, Qb, MM, EE, EE);
  gemm_bt<false><<<dim3(8,64), 256, 0, stream>>>(yb, Wkt, bk, Kb, MM, EE, EE);
  gemm_bt<false><<<dim3(8,64), 256, 0, stream>>>(yb, Wvt, bv, Vb, MM, EE, EE);
  transpose_v<<<dim3(32,16,2), 256, 0, stream>>>(Vb, Vtb);
  attn<<<512, 512, 0, stream>>>(Qb, Kb, Vtb, Atb);
  gemm_bt<true><<<dim3(8,64), 256, 0, stream>>>(Atb, Wot, bo, d_out, MM, EE, EE);
}

// Round 6
// 149.165 us; speedup vs baseline: 1.7604x; 1.0961x over previous
//
#include <hip/hip_runtime.h>
#include <stdint.h>

#define BB 2
#define TT 2048
#define EE 1024
#define HH 16
#define DD 64
#define MM (BB*TT)   // 4096 rows

typedef unsigned short u16;
typedef __attribute__((ext_vector_type(4))) float f32x4;
typedef __attribute__((ext_vector_type(8))) __bf16 bf16x8;
typedef __attribute__((ext_vector_type(8))) u16 u16x8;

union FragU { u16x8 u; bf16x8 b; };
union BfU { __bf16 h; u16 u; };

__device__ __forceinline__ u16 f2bf(float f) {
  uint32_t u = __float_as_uint(f);
  u += 0x7fffu + ((u >> 16) & 1u);   // RNE (inputs are finite)
  return (u16)(u >> 16);
}

// ---------------- f32 -> bf16 convert (8 elems/thread) ----------------
__global__ __launch_bounds__(256) void cvt_f32_bf16(const float* __restrict__ src,
                                                    u16* __restrict__ dst, int n8) {
  int i = blockIdx.x * 256 + threadIdx.x;
  if (i >= n8) return;
  const f32x4* s4 = (const f32x4*)src;
  f32x4 a = s4[2*i], b = s4[2*i+1];
  u16x8 o;
  o[0]=f2bf(a[0]); o[1]=f2bf(a[1]); o[2]=f2bf(a[2]); o[3]=f2bf(a[3]);
  o[4]=f2bf(b[0]); o[5]=f2bf(b[1]); o[6]=f2bf(b[2]); o[7]=f2bf(b[3]);
  ((u16x8*)dst)[i] = o;
}

// ---------------- weight transpose + convert: Wt[n][k] = bf16(W[k][n]) ----------------
__global__ __launch_bounds__(256) void wt_cvt4(const float* __restrict__ W0, const float* __restrict__ W1,
                                               const float* __restrict__ W2, const float* __restrict__ W3,
                                               u16* __restrict__ T0, u16* __restrict__ T1,
                                               u16* __restrict__ T2, u16* __restrict__ T3) {
  const float* W; u16* Tp;
  switch (blockIdx.z) {
    case 0: W = W0; Tp = T0; break;
    case 1: W = W1; Tp = T1; break;
    case 2: W = W2; Tp = T2; break;
    default: W = W3; Tp = T3; break;
  }
  int n0 = blockIdx.x * 64, k0 = blockIdx.y * 64;
  __shared__ alignas(16) float tile[64][65];
  int t = threadIdx.x;
#pragma unroll
  for (int i = 0; i < 16; ++i) {
    int idx = i*256 + t; int r = idx >> 6, c = idx & 63;
    tile[r][c] = W[(size_t)(k0 + r) * EE + n0 + c];
  }
  __syncthreads();
#pragma unroll
  for (int i = 0; i < 16; ++i) {
    int idx = i*256 + t; int rn = idx >> 6, ck = idx & 63;
    Tp[(size_t)(n0 + rn) * EE + k0 + ck] = f2bf(tile[ck][rn]);
  }
}

// ---------------- GEMM: C[M][N] = (A[M][K] @ Bt[N][K]^T + bias[N]) * oscale ----------------
// 64x128 tile, BK=64, 4 waves (2x2: 32-row x 64-col quadrants), 16x16x32 bf16 MFMA.
// Grid = (N/128, M/64) = 512 blocks -> 2 blocks/CU. Register-prefetch staging.
template <bool F32OUT>
__global__ __launch_bounds__(256) void gemm_bt(const u16* __restrict__ A, const u16* __restrict__ Bt,
                                               const float* __restrict__ bias, void* __restrict__ Cout,
                                               int M, int N, int K, float oscale) {
  __shared__ alignas(16) u16 As[64][72];
  __shared__ alignas(16) u16 Bs[128][72];
  const int t = threadIdx.x;
  const int lane = t & 63, wave = t >> 6;
  const int wr = wave >> 1, wc = wave & 1;
  const int bm = blockIdx.y, bn = blockIdx.x;

  f32x4 acc[2][4] = {};

  const int srow = t >> 3;            // 0..31
  const int scol = (t & 7) * 8;       // u16 col 0..56
  const u16* Ag = A + (size_t)(bm * 64) * K;
  const u16* Bg = Bt + (size_t)(bn * 128) * K;

  u16x8 ra[2], rb[4];
#pragma unroll
  for (int r = 0; r < 2; ++r)
    ra[r] = *(const u16x8*)(Ag + (size_t)(r*32 + srow) * K + scol);
#pragma unroll
  for (int r = 0; r < 4; ++r)
    rb[r] = *(const u16x8*)(Bg + (size_t)(r*32 + srow) * K + scol);

  const int nk = K / 64;
  for (int kt = 0; kt < nk; ++kt) {
    __syncthreads();
#pragma unroll
    for (int r = 0; r < 2; ++r) *(u16x8*)&As[r*32 + srow][scol] = ra[r];
#pragma unroll
    for (int r = 0; r < 4; ++r) *(u16x8*)&Bs[r*32 + srow][scol] = rb[r];
    __syncthreads();
    if (kt + 1 < nk) {
      const int k0 = (kt + 1) * 64;
#pragma unroll
      for (int r = 0; r < 2; ++r)
        ra[r] = *(const u16x8*)(Ag + (size_t)(r*32 + srow) * K + k0 + scol);
#pragma unroll
      for (int r = 0; r < 4; ++r)
        rb[r] = *(const u16x8*)(Bg + (size_t)(r*32 + srow) * K + k0 + scol);
    }
#pragma unroll
    for (int ks = 0; ks < 2; ++ks) {
      const int kc = ks*32 + ((lane >> 4) << 3);
      FragU af[2], bfr[4];
#pragma unroll
      for (int mi = 0; mi < 2; ++mi)
        af[mi].u = *(const u16x8*)&As[wr*32 + mi*16 + (lane & 15)][kc];
#pragma unroll
      for (int nj = 0; nj < 4; ++nj)
        bfr[nj].u = *(const u16x8*)&Bs[wc*64 + nj*16 + (lane & 15)][kc];
#pragma unroll
      for (int mi = 0; mi < 2; ++mi)
#pragma unroll
        for (int nj = 0; nj < 4; ++nj)
          acc[mi][nj] = __builtin_amdgcn_mfma_f32_16x16x32_bf16(af[mi].b, bfr[nj].b, acc[mi][nj], 0, 0, 0);
    }
  }

  // epilogue: bias + scale + store. C/D layout: col=lane&15, row=(lane>>4)*4+reg
  const int cbase = bn*128 + wc*64 + (lane & 15);
  float bv[4];
#pragma unroll
  for (int nj = 0; nj < 4; ++nj) bv[nj] = bias[cbase + nj*16];
#pragma unroll
  for (int mi = 0; mi < 2; ++mi) {
    int row0 = bm*64 + wr*32 + mi*16 + ((lane >> 4) << 2);
#pragma unroll
    for (int i = 0; i < 4; ++i) {
      if (F32OUT) {
        float* Cp = (float*)Cout + (size_t)(row0 + i) * N + cbase;
#pragma unroll
        for (int nj = 0; nj < 4; ++nj)
          Cp[nj*16] = (acc[mi][nj][i] + bv[nj]) * oscale;
      } else {
        u16* Cp = (u16*)Cout + (size_t)(row0 + i) * N + cbase;
#pragma unroll
        for (int nj = 0; nj < 4; ++nj)
          Cp[nj*16] = f2bf((acc[mi][nj][i] + bv[nj]) * oscale);
      }
    }
  }
}

// ---------------- V transpose: V[b][t][h][d] -> Vt[b][h][d][t] ----------------
__global__ __launch_bounds__(256) void transpose_v(const u16* __restrict__ V, u16* __restrict__ Vt) {
  int tb = blockIdx.x, h = blockIdx.y, b = blockIdx.z;
  __shared__ alignas(16) u16 tile[64][66];
  int t = threadIdx.x;
  int t0 = tb * 64;
#pragma unroll
  for (int i = 0; i < 16; ++i) {
    int idx = i*256 + t; int r = idx >> 6, c = idx & 63;
    tile[r][c] = V[(size_t)(b*TT + t0 + r) * EE + h*DD + c];
  }
  __syncthreads();
#pragma unroll
  for (int i = 0; i < 16; ++i) {
    int idx = i*256 + t; int dd = idx >> 6, tt2 = idx & 63;
    Vt[((size_t)(b*HH + h) * DD + dd) * TT + t0 + tt2] = tile[tt2][dd];
  }
}

// ---------------- causal flash attention (MFMA, 4 waves x 16 q-rows, QBLK=64) ----------------
// Grid = 1024 blocks, LPT-ordered: blockIdx i -> qt = 31-(i>>5) so longest blocks
// dispatch first. Q is pre-scaled by scale*log2(e). Wave-uniform running max +
// defer-max (THR=8, log2 domain) + lane-local l partials (end reduce).
__global__ __launch_bounds__(256) void attn(const u16* __restrict__ Q, const u16* __restrict__ K,
                                            const u16* __restrict__ Vt, u16* __restrict__ O) {
  const int i0 = blockIdx.x;
  const int qt = 31 - (i0 >> 5);
  const int bh = i0 & 31;
  const int b = bh >> 4, h = bh & 15;

  const int t = threadIdx.x, lane = t & 63, w = t >> 6;
  __shared__ alignas(16) u16 Ks[64][72];
  __shared__ alignas(16) u16 Vs[64][72];
  __shared__ alignas(16) u16 Ps[4][16][72];   // wave-private P tiles

  const int qw0 = qt * 64 + w * 16;           // 16 q-rows per wave

  // hoist Q fragments: row qw0 + (lane&15), d = ks*32 + (lane>>4)*8 + 0..7
  FragU qf[2];
  const u16* Qbase = Q + ((size_t)(b*TT) + qw0) * EE + h*DD;
#pragma unroll
  for (int ks = 0; ks < 2; ++ks) {
    int col = ks*32 + ((lane >> 4) << 3);
    qf[ks].u = *(const u16x8*)(Qbase + (size_t)(lane & 15) * EE + col);
  }

  f32x4 oacc[4] = {};
  float l_part[4] = {0.f, 0.f, 0.f, 0.f};
  float m_run = -1e30f;

  const u16* Kbase = K + (size_t)(b*TT) * EE + h*DD;
  const u16* Vtbase = Vt + (size_t)(b*HH + h) * DD * TT;

  const int nkv = qt + 1;
  // prefetch tile 0 (256 threads: 2 chunks each for K and V^T)
  u16x8 rk[2], rv[2];
#pragma unroll
  for (int p = 0; p < 2; ++p) {
    int idx = p*256 + t; int r = idx >> 3, c = (idx & 7) * 8;
    rk[p] = *(const u16x8*)(Kbase + (size_t)r * EE + c);
    rv[p] = *(const u16x8*)(Vtbase + (size_t)r * TT + c);
  }

  for (int j = 0; j < nkv; ++j) {
    const int kv0 = j * 64;
    __syncthreads();
#pragma unroll
    for (int p = 0; p < 2; ++p) {
      int idx = p*256 + t; int r = idx >> 3, c = (idx & 7) * 8;
      *(u16x8*)&Ks[r][c] = rk[p];
      *(u16x8*)&Vs[r][c] = rv[p];
    }
    __syncthreads();
    if (j + 1 < nkv) {
      const int kv1 = kv0 + 64;
#pragma unroll
      for (int p = 0; p < 2; ++p) {
        int idx = p*256 + t; int r = idx >> 3, c = (idx & 7) * 8;
        rk[p] = *(const u16x8*)(Kbase + (size_t)(kv1 + r) * EE + c);
        rv[p] = *(const u16x8*)(Vtbase + (size_t)r * TT + kv1 + c);
      }
    }
    if (kv0 > qw0 + 15) continue;   // wave fully masked in this tile

    // S = Q K^T  (row q = qw0+(lane>>4)*4+i, col kv = kv0+nj*16+(lane&15)); Q pre-scaled
    f32x4 s[4] = {};
    __builtin_amdgcn_s_setprio(1);
#pragma unroll
    for (int ks = 0; ks < 2; ++ks) {
      const int kc = ks*32 + ((lane >> 4) << 3);
      FragU kf[4];
#pragma unroll
      for (int nj = 0; nj < 4; ++nj)
        kf[nj].u = *(const u16x8*)&Ks[nj*16 + (lane & 15)][kc];
#pragma unroll
      for (int nj = 0; nj < 4; ++nj)
        s[nj] = __builtin_amdgcn_mfma_f32_16x16x32_bf16(qf[ks].b, kf[nj].b, s[nj], 0, 0, 0);
    }
    __builtin_amdgcn_s_setprio(0);

    const bool full = (kv0 + 63 <= qw0);
    float tv[4][4];
    float vmax = -1e30f;
#pragma unroll
    for (int i = 0; i < 4; ++i) {
      int row = qw0 + ((lane >> 4) << 2) + i;
#pragma unroll
      for (int nj = 0; nj < 4; ++nj) {
        float xv = s[nj][i];
        if (!full) {
          int col = kv0 + nj*16 + (lane & 15);
          if (col > row) xv = -1e30f;
        }
        tv[i][nj] = xv;
        vmax = fmaxf(vmax, xv);
      }
    }
    // wave-wide max (6 shuffles); wave-uniform m upper-bounds every row
    vmax = fmaxf(vmax, __shfl_xor(vmax, 1));
    vmax = fmaxf(vmax, __shfl_xor(vmax, 2));
    vmax = fmaxf(vmax, __shfl_xor(vmax, 4));
    vmax = fmaxf(vmax, __shfl_xor(vmax, 8));
    vmax = fmaxf(vmax, __shfl_xor(vmax, 16));
    vmax = fmaxf(vmax, __shfl_xor(vmax, 32));

    if (vmax > m_run + 8.f) {        // wave-uniform defer-max rescale (rare after tile 0)
      float f = exp2f(m_run - vmax); // 0 on first tile
#pragma unroll
      for (int i = 0; i < 4; ++i) l_part[i] *= f;
#pragma unroll
      for (int dj = 0; dj < 4; ++dj)
#pragma unroll
        for (int i = 0; i < 4; ++i) oacc[dj][i] *= f;
      m_run = vmax;
    }

#pragma unroll
    for (int i = 0; i < 4; ++i) {
      int prow = ((lane >> 4) << 2) + i;
      float psum = 0.f;
#pragma unroll
      for (int nj = 0; nj < 4; ++nj) {
        float p = exp2f(tv[i][nj] - m_run);
        psum += p;
        BfU cv; cv.h = (__bf16)p;
        Ps[w][prow][nj*16 + (lane & 15)] = cv.u;
      }
      l_part[i] += psum;
    }

    // O += P @ V
    __builtin_amdgcn_s_setprio(1);
#pragma unroll
    for (int ks = 0; ks < 2; ++ks) {
      const int kc = ks*32 + ((lane >> 4) << 3);
      FragU pf, vf[4];
      pf.u = *(const u16x8*)&Ps[w][lane & 15][kc];
#pragma unroll
      for (int dj = 0; dj < 4; ++dj)
        vf[dj].u = *(const u16x8*)&Vs[dj*16 + (lane & 15)][kc];
#pragma unroll
      for (int dj = 0; dj < 4; ++dj)
        oacc[dj] = __builtin_amdgcn_mfma_f32_16x16x32_bf16(pf.b, vf[dj].b, oacc[dj], 0, 0, 0);
    }
    __builtin_amdgcn_s_setprio(0);
  }

  // end: reduce l partials across the 16 lanes holding each row, then store
#pragma unroll
  for (int i = 0; i < 4; ++i) {
    l_part[i] += __shfl_xor(l_part[i], 1);
    l_part[i] += __shfl_xor(l_part[i], 2);
    l_part[i] += __shfl_xor(l_part[i], 4);
    l_part[i] += __shfl_xor(l_part[i], 8);
  }
  u16* Ob = O + ((size_t)(b*TT) + qw0) * EE + h*DD;
#pragma unroll
  for (int i = 0; i < 4; ++i) {
    float inv = 1.f / l_part[i];
    int row = ((lane >> 4) << 2) + i;
#pragma unroll
    for (int dj = 0; dj < 4; ++dj)
      Ob[(size_t)row * EE + dj*16 + (lane & 15)] = f2bf(oacc[dj][i] * inv);
  }
}

// ---------------- launch ----------------
extern "C" void kernel_launch(void* const* d_in, const int* in_sizes, int n_in,
                              void* d_out, int out_size, void* d_ws, size_t ws_size,
                              hipStream_t stream) {
  const float* x  = (const float*)d_in[0];
  const float* y  = (const float*)d_in[1];
  // d_in[2] = mask (tril causal; implemented analytically)
  const float* Wq = (const float*)d_in[3];
  const float* bq = (const float*)d_in[4];
  const float* Wk = (const float*)d_in[5];
  const float* bk = (const float*)d_in[6];
  const float* Wv = (const float*)d_in[7];
  const float* bv = (const float*)d_in[8];
  const float* Wo = (const float*)d_in[9];
  const float* bo = (const float*)d_in[10];

  if (ws_size < (size_t)67108864) return;  // need 64 MiB scratch

  char* ws = (char*)d_ws;
  u16* xb  = (u16*)(ws + 0);
  u16* yb  = (u16*)(ws + 8388608);
  u16* Wqt = (u16*)(ws + 16777216);
  u16* Wkt = (u16*)(ws + 18874368);
  u16* Wvt = (u16*)(ws + 20971520);
  u16* Wot = (u16*)(ws + 23068672);
  u16* Qb  = (u16*)(ws + 25165824);
  u16* Kb  = (u16*)(ws + 33554432);
  u16* Vb  = (u16*)(ws + 41943040);
  u16* Vtb = (u16*)(ws + 50331648);
  u16* Atb = (u16*)(ws + 58720256);

  const float c1 = 0.125f * 1.44269504088896340736f;  // scale * log2(e), folded into Q

  cvt_f32_bf16<<<2048, 256, 0, stream>>>(x, xb, MM*EE/8);
  cvt_f32_bf16<<<2048, 256, 0, stream>>>(y, yb, MM*EE/8);
  wt_cvt4<<<dim3(16,16,4), 256, 0, stream>>>(Wq, Wk, Wv, Wo, Wqt, Wkt, Wvt, Wot);
  gemm_bt<false><<<dim3(8,64), 256, 0, stream>>>(xb, Wqt, bq, Qb, MM, EE, EE, c1);
  gemm_bt<false><<<dim3(8,64), 256, 0, stream>>>(yb, Wkt, bk, Kb, MM, EE, EE, 1.0f);
  gemm_bt<false><<<dim3(8,64), 256, 0, stream>>>(yb, Wvt, bv, Vb, MM, EE, EE, 1.0f);
  transpose_v<<<dim3(32,16,2), 256, 0, stream>>>(Vb, Vtb);
  attn<<<1024, 256, 0, stream>>>(Qb, Kb, Vtb, Atb);
  gemm_bt<true><<<dim3(8,64), 256, 0, stream>>>(Atb, Wot, bo, d_out, MM, EE, EE, 1.0f);
}

// Round 7
// 136.077 us; speedup vs baseline: 1.9298x; 1.0962x over previous
//
#include <hip/hip_runtime.h>
#include <stdint.h>

#define BB 2
#define TT 2048
#define EE 1024
#define HH 16
#define DD 64
#define MM (BB*TT)   // 4096 rows

typedef unsigned short u16;
typedef __attribute__((ext_vector_type(4))) float f32x4;
typedef __attribute__((ext_vector_type(8))) __bf16 bf16x8;
typedef __attribute__((ext_vector_type(8))) u16 u16x8;

union FragU { u16x8 u; bf16x8 b; };
union BfU { __bf16 h; u16 u; };

__device__ __forceinline__ u16 f2bf(float f) {
  uint32_t u = __float_as_uint(f);
  u += 0x7fffu + ((u >> 16) & 1u);   // RNE (inputs are finite)
  return (u16)(u >> 16);
}

__device__ __forceinline__ u16x8 cvt8(f32x4 a, f32x4 b) {
  u16x8 o;
  o[0]=f2bf(a[0]); o[1]=f2bf(a[1]); o[2]=f2bf(a[2]); o[3]=f2bf(a[3]);
  o[4]=f2bf(b[0]); o[5]=f2bf(b[1]); o[6]=f2bf(b[2]); o[7]=f2bf(b[3]);
  return o;
}

// ---------------- weight transpose + convert: Wt[n][k] = bf16(W[k][n]) ----------------
__global__ __launch_bounds__(256) void wt_cvt4(const float* __restrict__ W0, const float* __restrict__ W1,
                                               const float* __restrict__ W2, const float* __restrict__ W3,
                                               u16* __restrict__ T0, u16* __restrict__ T1,
                                               u16* __restrict__ T2, u16* __restrict__ T3) {
  const float* W; u16* Tp;
  switch (blockIdx.z) {
    case 0: W = W0; Tp = T0; break;
    case 1: W = W1; Tp = T1; break;
    case 2: W = W2; Tp = T2; break;
    default: W = W3; Tp = T3; break;
  }
  int n0 = blockIdx.x * 64, k0 = blockIdx.y * 64;
  __shared__ alignas(16) float tile[64][65];
  int t = threadIdx.x;
#pragma unroll
  for (int i = 0; i < 16; ++i) {
    int idx = i*256 + t; int r = idx >> 6, c = idx & 63;
    tile[r][c] = W[(size_t)(k0 + r) * EE + n0 + c];
  }
  __syncthreads();
#pragma unroll
  for (int i = 0; i < 16; ++i) {
    int idx = i*256 + t; int rn = idx >> 6, ck = idx & 63;
    Tp[(size_t)(n0 + rn) * EE + k0 + ck] = f2bf(tile[ck][rn]);
  }
}

// ---------------- GEMM: C[M][N] = (A[M][K] @ Bt[N][K]^T + bias[N]) * oscale ----------------
// 64x128 tile, BK=64, 4 waves (2x2: 32-row x 64-col quadrants), 16x16x32 bf16 MFMA.
// AF32: A is f32, converted to bf16 on the fly during staging.
// bias: cols < nsplit -> bias0[c], else bias1[c - nsplit] (block-uniform since nsplit % 128 == 0).
template <bool AF32, bool F32OUT>
__global__ __launch_bounds__(256) void gemm_bt(const void* __restrict__ A, const u16* __restrict__ Bt,
                                               const float* __restrict__ bias0, const float* __restrict__ bias1,
                                               int nsplit, void* __restrict__ Cout,
                                               int M, int N, int K, float oscale) {
  __shared__ alignas(16) u16 As[64][72];
  __shared__ alignas(16) u16 Bs[128][72];
  const int t = threadIdx.x;
  const int lane = t & 63, wave = t >> 6;
  const int wr = wave >> 1, wc = wave & 1;
  const int bm = blockIdx.y, bn = blockIdx.x;

  f32x4 acc[2][4] = {};

  const int srow = t >> 3;            // 0..31
  const int scol = (t & 7) * 8;       // elem col 0..56
  const u16* Ag16 = (const u16*)A + (size_t)(bm * 64) * K;
  const float* Ag32 = (const float*)A + (size_t)(bm * 64) * K;
  const u16* Bg = Bt + (size_t)(bn * 128) * K;

  u16x8 ra[2], rb[4];
#pragma unroll
  for (int r = 0; r < 2; ++r) {
    if (AF32) {
      const float* p = Ag32 + (size_t)(r*32 + srow) * K + scol;
      ra[r] = cvt8(*(const f32x4*)p, *(const f32x4*)(p + 4));
    } else {
      ra[r] = *(const u16x8*)(Ag16 + (size_t)(r*32 + srow) * K + scol);
    }
  }
#pragma unroll
  for (int r = 0; r < 4; ++r)
    rb[r] = *(const u16x8*)(Bg + (size_t)(r*32 + srow) * K + scol);

  const int nk = K / 64;
  for (int kt = 0; kt < nk; ++kt) {
    __syncthreads();
#pragma unroll
    for (int r = 0; r < 2; ++r) *(u16x8*)&As[r*32 + srow][scol] = ra[r];
#pragma unroll
    for (int r = 0; r < 4; ++r) *(u16x8*)&Bs[r*32 + srow][scol] = rb[r];
    __syncthreads();
    if (kt + 1 < nk) {
      const int k0 = (kt + 1) * 64;
#pragma unroll
      for (int r = 0; r < 2; ++r) {
        if (AF32) {
          const float* p = Ag32 + (size_t)(r*32 + srow) * K + k0 + scol;
          ra[r] = cvt8(*(const f32x4*)p, *(const f32x4*)(p + 4));
        } else {
          ra[r] = *(const u16x8*)(Ag16 + (size_t)(r*32 + srow) * K + k0 + scol);
        }
      }
#pragma unroll
      for (int r = 0; r < 4; ++r)
        rb[r] = *(const u16x8*)(Bg + (size_t)(r*32 + srow) * K + k0 + scol);
    }
#pragma unroll
    for (int ks = 0; ks < 2; ++ks) {
      const int kc = ks*32 + ((lane >> 4) << 3);
      FragU af[2], bfr[4];
#pragma unroll
      for (int mi = 0; mi < 2; ++mi)
        af[mi].u = *(const u16x8*)&As[wr*32 + mi*16 + (lane & 15)][kc];
#pragma unroll
      for (int nj = 0; nj < 4; ++nj)
        bfr[nj].u = *(const u16x8*)&Bs[wc*64 + nj*16 + (lane & 15)][kc];
#pragma unroll
      for (int mi = 0; mi < 2; ++mi)
#pragma unroll
        for (int nj = 0; nj < 4; ++nj)
          acc[mi][nj] = __builtin_amdgcn_mfma_f32_16x16x32_bf16(af[mi].b, bfr[nj].b, acc[mi][nj], 0, 0, 0);
    }
  }

  // epilogue: bias + scale + store. C/D layout: col=lane&15, row=(lane>>4)*4+reg
  const int cbase = bn*128 + wc*64 + (lane & 15);
  const float* bp = (bn*128 < nsplit) ? bias0 : (bias1 - nsplit);
  float bv[4];
#pragma unroll
  for (int nj = 0; nj < 4; ++nj) bv[nj] = bp[cbase + nj*16];
#pragma unroll
  for (int mi = 0; mi < 2; ++mi) {
    int row0 = bm*64 + wr*32 + mi*16 + ((lane >> 4) << 2);
#pragma unroll
    for (int i = 0; i < 4; ++i) {
      if (F32OUT) {
        float* Cp = (float*)Cout + (size_t)(row0 + i) * N + cbase;
#pragma unroll
        for (int nj = 0; nj < 4; ++nj)
          Cp[nj*16] = (acc[mi][nj][i] + bv[nj]) * oscale;
      } else {
        u16* Cp = (u16*)Cout + (size_t)(row0 + i) * N + cbase;
#pragma unroll
        for (int nj = 0; nj < 4; ++nj)
          Cp[nj*16] = f2bf((acc[mi][nj][i] + bv[nj]) * oscale);
      }
    }
  }
}

// ---------------- V transpose: KV[b*T+t][1024 + h*64 + d] -> Vt[b][h][d][t] ----------------
__global__ __launch_bounds__(256) void transpose_v(const u16* __restrict__ KV, u16* __restrict__ Vt) {
  int tb = blockIdx.x, h = blockIdx.y, b = blockIdx.z;
  __shared__ alignas(16) u16 tile[64][66];
  int t = threadIdx.x;
  int t0 = tb * 64;
#pragma unroll
  for (int i = 0; i < 16; ++i) {
    int idx = i*256 + t; int r = idx >> 6, c = idx & 63;
    tile[r][c] = KV[(size_t)(b*TT + t0 + r) * 2048 + 1024 + h*DD + c];
  }
  __syncthreads();
#pragma unroll
  for (int i = 0; i < 16; ++i) {
    int idx = i*256 + t; int dd = idx >> 6, tt2 = idx & 63;
    Vt[((size_t)(b*HH + h) * DD + dd) * TT + t0 + tt2] = tile[tt2][dd];
  }
}

// ---------------- causal flash attention (MFMA, 4 waves x 16 q-rows, QBLK=64) ----------------
// Grid = 1024 blocks, LPT-ordered (qt = 31-(i>>5)). Q pre-scaled by scale*log2(e).
// Ballot-guarded defer-max (THR=8, log2 domain), lane-local l partials (end reduce).
// K read from fused KV buffer (row stride 2048).
__global__ __launch_bounds__(256) void attn(const u16* __restrict__ Q, const u16* __restrict__ KV,
                                            const u16* __restrict__ Vt, u16* __restrict__ O) {
  const int i0 = blockIdx.x;
  const int qt = 31 - (i0 >> 5);
  const int bh = i0 & 31;
  const int b = bh >> 4, h = bh & 15;

  const int t = threadIdx.x, lane = t & 63, w = t >> 6;
  __shared__ alignas(16) u16 Ks[64][72];
  __shared__ alignas(16) u16 Vs[64][72];
  __shared__ alignas(16) u16 Ps[4][16][72];   // wave-private P tiles

  const int qw0 = qt * 64 + w * 16;           // 16 q-rows per wave

  // hoist Q fragments: row qw0 + (lane&15), d = ks*32 + (lane>>4)*8 + 0..7
  FragU qf[2];
  const u16* Qbase = Q + ((size_t)(b*TT) + qw0) * EE + h*DD;
#pragma unroll
  for (int ks = 0; ks < 2; ++ks) {
    int col = ks*32 + ((lane >> 4) << 3);
    qf[ks].u = *(const u16x8*)(Qbase + (size_t)(lane & 15) * EE + col);
  }

  f32x4 oacc[4] = {};
  float l_part[4] = {0.f, 0.f, 0.f, 0.f};
  float m_run = -1e30f;

  const u16* Kbase = KV + (size_t)(b*TT) * 2048 + h*DD;     // K part: cols 0..1023
  const u16* Vtbase = Vt + (size_t)(b*HH + h) * DD * TT;

  const int nkv = qt + 1;
  // prefetch tile 0 (256 threads: 2 chunks each for K and V^T)
  u16x8 rk[2], rv[2];
#pragma unroll
  for (int p = 0; p < 2; ++p) {
    int idx = p*256 + t; int r = idx >> 3, c = (idx & 7) * 8;
    rk[p] = *(const u16x8*)(Kbase + (size_t)r * 2048 + c);
    rv[p] = *(const u16x8*)(Vtbase + (size_t)r * TT + c);
  }

  for (int j = 0; j < nkv; ++j) {
    const int kv0 = j * 64;
    __syncthreads();
#pragma unroll
    for (int p = 0; p < 2; ++p) {
      int idx = p*256 + t; int r = idx >> 3, c = (idx & 7) * 8;
      *(u16x8*)&Ks[r][c] = rk[p];
      *(u16x8*)&Vs[r][c] = rv[p];
    }
    __syncthreads();
    if (j + 1 < nkv) {
      const int kv1 = kv0 + 64;
#pragma unroll
      for (int p = 0; p < 2; ++p) {
        int idx = p*256 + t; int r = idx >> 3, c = (idx & 7) * 8;
        rk[p] = *(const u16x8*)(Kbase + (size_t)(kv1 + r) * 2048 + c);
        rv[p] = *(const u16x8*)(Vtbase + (size_t)r * TT + kv1 + c);
      }
    }
    if (kv0 > qw0 + 15) continue;   // wave fully masked in this tile

    // S = Q K^T  (row q = qw0+(lane>>4)*4+i, col kv = kv0+nj*16+(lane&15)); Q pre-scaled
    f32x4 s[4] = {};
    __builtin_amdgcn_s_setprio(1);
#pragma unroll
    for (int ks = 0; ks < 2; ++ks) {
      const int kc = ks*32 + ((lane >> 4) << 3);
      FragU kf[4];
#pragma unroll
      for (int nj = 0; nj < 4; ++nj)
        kf[nj].u = *(const u16x8*)&Ks[nj*16 + (lane & 15)][kc];
#pragma unroll
      for (int nj = 0; nj < 4; ++nj)
        s[nj] = __builtin_amdgcn_mfma_f32_16x16x32_bf16(qf[ks].b, kf[nj].b, s[nj], 0, 0, 0);
    }
    __builtin_amdgcn_s_setprio(0);

    const bool full = (kv0 + 63 <= qw0);
    float tv[4][4];
    float vmax = -1e30f;
#pragma unroll
    for (int i = 0; i < 4; ++i) {
      int row = qw0 + ((lane >> 4) << 2) + i;
#pragma unroll
      for (int nj = 0; nj < 4; ++nj) {
        float xv = s[nj][i];
        if (!full) {
          int col = kv0 + nj*16 + (lane & 15);
          if (col > row) xv = -1e30f;
        }
        tv[i][nj] = xv;
        vmax = fmaxf(vmax, xv);
      }
    }
    // ballot-guarded defer-max: common path = 1 vote, no shuffles
    if (__any(vmax > m_run + 8.f)) {
      float vm = vmax;
      vm = fmaxf(vm, __shfl_xor(vm, 1));
      vm = fmaxf(vm, __shfl_xor(vm, 2));
      vm = fmaxf(vm, __shfl_xor(vm, 4));
      vm = fmaxf(vm, __shfl_xor(vm, 8));
      vm = fmaxf(vm, __shfl_xor(vm, 16));
      vm = fmaxf(vm, __shfl_xor(vm, 32));
      float f = exp2f(m_run - vm);   // 0 on first tile
#pragma unroll
      for (int i = 0; i < 4; ++i) l_part[i] *= f;
#pragma unroll
      for (int dj = 0; dj < 4; ++dj)
#pragma unroll
        for (int i = 0; i < 4; ++i) oacc[dj][i] *= f;
      m_run = vm;
    }

#pragma unroll
    for (int i = 0; i < 4; ++i) {
      int prow = ((lane >> 4) << 2) + i;
      float psum = 0.f;
#pragma unroll
      for (int nj = 0; nj < 4; ++nj) {
        float p = exp2f(tv[i][nj] - m_run);
        psum += p;
        BfU cv; cv.h = (__bf16)p;
        Ps[w][prow][nj*16 + (lane & 15)] = cv.u;
      }
      l_part[i] += psum;
    }

    // O += P @ V
    __builtin_amdgcn_s_setprio(1);
#pragma unroll
    for (int ks = 0; ks < 2; ++ks) {
      const int kc = ks*32 + ((lane >> 4) << 3);
      FragU pf, vf[4];
      pf.u = *(const u16x8*)&Ps[w][lane & 15][kc];
#pragma unroll
      for (int dj = 0; dj < 4; ++dj)
        vf[dj].u = *(const u16x8*)&Vs[dj*16 + (lane & 15)][kc];
#pragma unroll
      for (int dj = 0; dj < 4; ++dj)
        oacc[dj] = __builtin_amdgcn_mfma_f32_16x16x32_bf16(pf.b, vf[dj].b, oacc[dj], 0, 0, 0);
    }
    __builtin_amdgcn_s_setprio(0);
  }

  // end: reduce l partials across the 16 lanes holding each row, then store
#pragma unroll
  for (int i = 0; i < 4; ++i) {
    l_part[i] += __shfl_xor(l_part[i], 1);
    l_part[i] += __shfl_xor(l_part[i], 2);
    l_part[i] += __shfl_xor(l_part[i], 4);
    l_part[i] += __shfl_xor(l_part[i], 8);
  }
  u16* Ob = O + ((size_t)(b*TT) + qw0) * EE + h*DD;
#pragma unroll
  for (int i = 0; i < 4; ++i) {
    float inv = 1.f / l_part[i];
    int row = ((lane >> 4) << 2) + i;
#pragma unroll
    for (int dj = 0; dj < 4; ++dj)
      Ob[(size_t)row * EE + dj*16 + (lane & 15)] = f2bf(oacc[dj][i] * inv);
  }
}

// ---------------- launch ----------------
extern "C" void kernel_launch(void* const* d_in, const int* in_sizes, int n_in,
                              void* d_out, int out_size, void* d_ws, size_t ws_size,
                              hipStream_t stream) {
  const float* x  = (const float*)d_in[0];
  const float* y  = (const float*)d_in[1];
  // d_in[2] = mask (tril causal; implemented analytically)
  const float* Wq = (const float*)d_in[3];
  const float* bq = (const float*)d_in[4];
  const float* Wk = (const float*)d_in[5];
  const float* bk = (const float*)d_in[6];
  const float* Wv = (const float*)d_in[7];
  const float* bv = (const float*)d_in[8];
  const float* Wo = (const float*)d_in[9];
  const float* bo = (const float*)d_in[10];

  if (ws_size < (size_t)50331648) return;  // need 48 MiB scratch

  char* ws = (char*)d_ws;
  u16* Wqt  = (u16*)(ws + 0);          // [1024][1024] bf16, 2 MiB
  u16* Wkvt = (u16*)(ws + 2097152);    // [2048][1024] bf16, 4 MiB ([Wk^T | Wv^T] rows)
  u16* Wot  = (u16*)(ws + 6291456);    // [1024][1024] bf16, 2 MiB
  u16* Qb   = (u16*)(ws + 8388608);    // [4096][1024] bf16, 8 MiB
  u16* KVb  = (u16*)(ws + 16777216);   // [4096][2048] bf16, 16 MiB ([K | V] cols)
  u16* Vtb  = (u16*)(ws + 33554432);   // [2][16][64][2048] bf16, 8 MiB
  u16* Atb  = (u16*)(ws + 41943040);   // [4096][1024] bf16, 8 MiB

  const float c1 = 0.125f * 1.44269504088896340736f;  // scale * log2(e), folded into Q

  wt_cvt4<<<dim3(16,16,4), 256, 0, stream>>>(Wq, Wk, Wv, Wo,
                                             Wqt, Wkvt, Wkvt + (size_t)1024*EE, Wot);
  gemm_bt<true,  false><<<dim3(8, 64), 256, 0, stream>>>(x, Wqt, bq, bq, EE, Qb, MM, 1024, EE, c1);
  gemm_bt<true,  false><<<dim3(16,64), 256, 0, stream>>>(y, Wkvt, bk, bv, 1024, KVb, MM, 2048, EE, 1.0f);
  transpose_v<<<dim3(32,16,2), 256, 0, stream>>>(KVb, Vtb);
  attn<<<1024, 256, 0, stream>>>(Qb, KVb, Vtb, Atb);
  gemm_bt<false, true><<<dim3(8, 64), 256, 0, stream>>>(Atb, Wot, bo, bo, EE, d_out, MM, 1024, EE, 1.0f);
}

// Round 8
// 135.311 us; speedup vs baseline: 1.9407x; 1.0057x over previous
//
#include <hip/hip_runtime.h>
#include <stdint.h>

#define BB 2
#define TT 2048
#define EE 1024
#define HH 16
#define DD 64
#define MM (BB*TT)   // 4096 rows

typedef unsigned short u16;
typedef __attribute__((ext_vector_type(4))) float f32x4;
typedef __attribute__((ext_vector_type(8))) __bf16 bf16x8;
typedef __attribute__((ext_vector_type(8))) u16 u16x8;
typedef __attribute__((ext_vector_type(4))) u16 u16x4;

union FragU { u16x8 u; bf16x8 b; };
union BfU { __bf16 h; u16 u; };

__device__ __forceinline__ u16 f2bf(float f) {
  uint32_t u = __float_as_uint(f);
  u += 0x7fffu + ((u >> 16) & 1u);   // RNE (inputs are finite)
  return (u16)(u >> 16);
}

__device__ __forceinline__ u16x8 cvt8(f32x4 a, f32x4 b) {
  u16x8 o;
  o[0]=f2bf(a[0]); o[1]=f2bf(a[1]); o[2]=f2bf(a[2]); o[3]=f2bf(a[3]);
  o[4]=f2bf(b[0]); o[5]=f2bf(b[1]); o[6]=f2bf(b[2]); o[7]=f2bf(b[3]);
  return o;
}

// ---------------- weight transpose + convert: Wt[n][k] = bf16(W[k][n]) ----------------
__global__ __launch_bounds__(256) void wt_cvt4(const float* __restrict__ W0, const float* __restrict__ W1,
                                               const float* __restrict__ W2, const float* __restrict__ W3,
                                               u16* __restrict__ T0, u16* __restrict__ T1,
                                               u16* __restrict__ T2, u16* __restrict__ T3) {
  const float* W; u16* Tp;
  switch (blockIdx.z) {
    case 0: W = W0; Tp = T0; break;
    case 1: W = W1; Tp = T1; break;
    case 2: W = W2; Tp = T2; break;
    default: W = W3; Tp = T3; break;
  }
  int n0 = blockIdx.x * 64, k0 = blockIdx.y * 64;
  __shared__ alignas(16) float tile[64][65];
  int t = threadIdx.x;
#pragma unroll
  for (int i = 0; i < 16; ++i) {
    int idx = i*256 + t; int r = idx >> 6, c = idx & 63;
    tile[r][c] = W[(size_t)(k0 + r) * EE + n0 + c];
  }
  __syncthreads();
#pragma unroll
  for (int i = 0; i < 16; ++i) {
    int idx = i*256 + t; int rn = idx >> 6, ck = idx & 63;
    Tp[(size_t)(n0 + rn) * EE + k0 + ck] = f2bf(tile[ck][rn]);
  }
}

// ---------------- GEMM: C[M][N] = (A[M][K] @ Bt[N][K]^T + bias[N]) * oscale ----------------
// 64x128 tile, BK=64, 4 waves (2x2: 32-row x 64-col quadrants), 16x16x32 bf16 MFMA.
// AF32: A is f32, converted to bf16 on the fly during staging.
// bias: cols < nsplit -> bias0[c], else bias1[c - nsplit] (block-uniform since nsplit % 128 == 0).
template <bool AF32, bool F32OUT>
__global__ __launch_bounds__(256) void gemm_bt(const void* __restrict__ A, const u16* __restrict__ Bt,
                                               const float* __restrict__ bias0, const float* __restrict__ bias1,
                                               int nsplit, void* __restrict__ Cout,
                                               int M, int N, int K, float oscale) {
  __shared__ alignas(16) u16 As[64][72];
  __shared__ alignas(16) u16 Bs[128][72];
  const int t = threadIdx.x;
  const int lane = t & 63, wave = t >> 6;
  const int wr = wave >> 1, wc = wave & 1;
  const int bm = blockIdx.y, bn = blockIdx.x;

  f32x4 acc[2][4] = {};

  const int srow = t >> 3;            // 0..31
  const int scol = (t & 7) * 8;       // elem col 0..56
  const u16* Ag16 = (const u16*)A + (size_t)(bm * 64) * K;
  const float* Ag32 = (const float*)A + (size_t)(bm * 64) * K;
  const u16* Bg = Bt + (size_t)(bn * 128) * K;

  u16x8 ra[2], rb[4];
#pragma unroll
  for (int r = 0; r < 2; ++r) {
    if (AF32) {
      const float* p = Ag32 + (size_t)(r*32 + srow) * K + scol;
      ra[r] = cvt8(*(const f32x4*)p, *(const f32x4*)(p + 4));
    } else {
      ra[r] = *(const u16x8*)(Ag16 + (size_t)(r*32 + srow) * K + scol);
    }
  }
#pragma unroll
  for (int r = 0; r < 4; ++r)
    rb[r] = *(const u16x8*)(Bg + (size_t)(r*32 + srow) * K + scol);

  const int nk = K / 64;
  for (int kt = 0; kt < nk; ++kt) {
    __syncthreads();
#pragma unroll
    for (int r = 0; r < 2; ++r) *(u16x8*)&As[r*32 + srow][scol] = ra[r];
#pragma unroll
    for (int r = 0; r < 4; ++r) *(u16x8*)&Bs[r*32 + srow][scol] = rb[r];
    __syncthreads();
    if (kt + 1 < nk) {
      const int k0 = (kt + 1) * 64;
#pragma unroll
      for (int r = 0; r < 2; ++r) {
        if (AF32) {
          const float* p = Ag32 + (size_t)(r*32 + srow) * K + k0 + scol;
          ra[r] = cvt8(*(const f32x4*)p, *(const f32x4*)(p + 4));
        } else {
          ra[r] = *(const u16x8*)(Ag16 + (size_t)(r*32 + srow) * K + k0 + scol);
        }
      }
#pragma unroll
      for (int r = 0; r < 4; ++r)
        rb[r] = *(const u16x8*)(Bg + (size_t)(r*32 + srow) * K + k0 + scol);
    }
#pragma unroll
    for (int ks = 0; ks < 2; ++ks) {
      const int kc = ks*32 + ((lane >> 4) << 3);
      FragU af[2], bfr[4];
#pragma unroll
      for (int mi = 0; mi < 2; ++mi)
        af[mi].u = *(const u16x8*)&As[wr*32 + mi*16 + (lane & 15)][kc];
#pragma unroll
      for (int nj = 0; nj < 4; ++nj)
        bfr[nj].u = *(const u16x8*)&Bs[wc*64 + nj*16 + (lane & 15)][kc];
#pragma unroll
      for (int mi = 0; mi < 2; ++mi)
#pragma unroll
        for (int nj = 0; nj < 4; ++nj)
          acc[mi][nj] = __builtin_amdgcn_mfma_f32_16x16x32_bf16(af[mi].b, bfr[nj].b, acc[mi][nj], 0, 0, 0);
    }
  }

  // epilogue: bias + scale + store. C/D layout: col=lane&15, row=(lane>>4)*4+reg
  const int cbase = bn*128 + wc*64 + (lane & 15);
  const float* bp = (bn*128 < nsplit) ? bias0 : (bias1 - nsplit);
  float bv[4];
#pragma unroll
  for (int nj = 0; nj < 4; ++nj) bv[nj] = bp[cbase + nj*16];
#pragma unroll
  for (int mi = 0; mi < 2; ++mi) {
    int row0 = bm*64 + wr*32 + mi*16 + ((lane >> 4) << 2);
#pragma unroll
    for (int i = 0; i < 4; ++i) {
      if (F32OUT) {
        float* Cp = (float*)Cout + (size_t)(row0 + i) * N + cbase;
#pragma unroll
        for (int nj = 0; nj < 4; ++nj)
          Cp[nj*16] = (acc[mi][nj][i] + bv[nj]) * oscale;
      } else {
        u16* Cp = (u16*)Cout + (size_t)(row0 + i) * N + cbase;
#pragma unroll
        for (int nj = 0; nj < 4; ++nj)
          Cp[nj*16] = f2bf((acc[mi][nj][i] + bv[nj]) * oscale);
      }
    }
  }
}

// ---------------- V transpose: KV[b*T+t][1024 + h*64 + d] -> Vt[b][h][d][t] ----------------
__global__ __launch_bounds__(256) void transpose_v(const u16* __restrict__ KV, u16* __restrict__ Vt) {
  int tb = blockIdx.x, h = blockIdx.y, b = blockIdx.z;
  __shared__ alignas(16) u16 tile[64][66];
  int t = threadIdx.x;
  int t0 = tb * 64;
#pragma unroll
  for (int i = 0; i < 16; ++i) {
    int idx = i*256 + t; int r = idx >> 6, c = idx & 63;
    tile[r][c] = KV[(size_t)(b*TT + t0 + r) * 2048 + 1024 + h*DD + c];
  }
  __syncthreads();
#pragma unroll
  for (int i = 0; i < 16; ++i) {
    int idx = i*256 + t; int dd = idx >> 6, tt2 = idx & 63;
    Vt[((size_t)(b*HH + h) * DD + dd) * TT + t0 + tt2] = tile[tt2][dd];
  }
}

// ---------------- causal flash attention (MFMA, swapped-QK^T, P in registers) ----------------
// Grid = 1024 blocks, LPT-ordered (qt = 31-(i>>5)). Q pre-scaled by scale*log2(e).
// QK^T computed as mfma(K,Q) so each lane holds S[kv-slice][q=lane&15] -> softmax and
// P->PV A-fragment stay in registers (no P LDS round-trip). PV B-operand (V^T) read with
// the matching permuted k-order kappa(g,j) = ks*32 + 16*(j>>2) + 4g + (j&3).
__global__ __launch_bounds__(256) void attn(const u16* __restrict__ Q, const u16* __restrict__ KV,
                                            const u16* __restrict__ Vt, u16* __restrict__ O) {
  const int i0 = blockIdx.x;
  const int qt = 31 - (i0 >> 5);
  const int bh = i0 & 31;
  const int b = bh >> 4, h = bh & 15;

  const int t = threadIdx.x, lane = t & 63, w = t >> 6;
  const int g = lane >> 4, c = lane & 15;
  __shared__ alignas(16) u16 Ks[64][72];
  __shared__ alignas(16) u16 Vs[64][72];

  const int qw0 = qt * 64 + w * 16;           // 16 q-rows per wave

  // hoist Q fragments (B-operand): row qw0 + c, d = ks*32 + g*8 + 0..7
  FragU qf[2];
  const u16* Qbase = Q + ((size_t)(b*TT) + qw0) * EE + h*DD;
#pragma unroll
  for (int ks = 0; ks < 2; ++ks)
    qf[ks].u = *(const u16x8*)(Qbase + (size_t)c * EE + ks*32 + g*8);

  f32x4 oacc[4] = {};
  float l_part = 0.f;
  float m_run = -1e30f;

  const u16* Kbase = KV + (size_t)(b*TT) * 2048 + h*DD;     // K part: cols 0..1023
  const u16* Vtbase = Vt + (size_t)(b*HH + h) * DD * TT;

  const int nkv = qt + 1;
  // prefetch tile 0 (256 threads: 2 chunks each for K and V^T)
  u16x8 rk[2], rv[2];
#pragma unroll
  for (int p = 0; p < 2; ++p) {
    int idx = p*256 + t; int r = idx >> 3, cc = (idx & 7) * 8;
    rk[p] = *(const u16x8*)(Kbase + (size_t)r * 2048 + cc);
    rv[p] = *(const u16x8*)(Vtbase + (size_t)r * TT + cc);
  }

  for (int j = 0; j < nkv; ++j) {
    const int kv0 = j * 64;
    __syncthreads();
#pragma unroll
    for (int p = 0; p < 2; ++p) {
      int idx = p*256 + t; int r = idx >> 3, cc = (idx & 7) * 8;
      *(u16x8*)&Ks[r][cc] = rk[p];
      *(u16x8*)&Vs[r][cc] = rv[p];
    }
    __syncthreads();
    if (j + 1 < nkv) {
      const int kv1 = kv0 + 64;
#pragma unroll
      for (int p = 0; p < 2; ++p) {
        int idx = p*256 + t; int r = idx >> 3, cc = (idx & 7) * 8;
        rk[p] = *(const u16x8*)(Kbase + (size_t)(kv1 + r) * 2048 + cc);
        rv[p] = *(const u16x8*)(Vtbase + (size_t)r * TT + kv1 + cc);
      }
    }
    if (kv0 > qw0 + 15) continue;   // wave fully masked in this tile

    // S^T = K Q^T: lane holds s[nj][r] = S[q = qw0+c][kv = kv0 + nj*16 + 4g + r]
    f32x4 s[4] = {};
    __builtin_amdgcn_s_setprio(1);
#pragma unroll
    for (int ks = 0; ks < 2; ++ks) {
      const int kc = ks*32 + g*8;
      FragU kf[4];
#pragma unroll
      for (int nj = 0; nj < 4; ++nj)
        kf[nj].u = *(const u16x8*)&Ks[nj*16 + c][kc];
#pragma unroll
      for (int nj = 0; nj < 4; ++nj)
        s[nj] = __builtin_amdgcn_mfma_f32_16x16x32_bf16(kf[nj].b, qf[ks].b, s[nj], 0, 0, 0);
    }
    __builtin_amdgcn_s_setprio(0);

    const bool full = (kv0 + 63 <= qw0);
    const int q = qw0 + c;
    float vmax = -1e30f;
#pragma unroll
    for (int nj = 0; nj < 4; ++nj)
#pragma unroll
      for (int r = 0; r < 4; ++r) {
        float xv = s[nj][r];
        if (!full) {
          if (kv0 + nj*16 + 4*g + r > q) xv = -1e30f;
        }
        s[nj][r] = xv;
        vmax = fmaxf(vmax, xv);
      }

    // ballot-guarded defer-max: common path = 1 vote
    if (__any(vmax > m_run + 8.f)) {
      float vm = vmax;
      vm = fmaxf(vm, __shfl_xor(vm, 1));
      vm = fmaxf(vm, __shfl_xor(vm, 2));
      vm = fmaxf(vm, __shfl_xor(vm, 4));
      vm = fmaxf(vm, __shfl_xor(vm, 8));
      vm = fmaxf(vm, __shfl_xor(vm, 16));
      vm = fmaxf(vm, __shfl_xor(vm, 32));
      float f = exp2f(m_run - vm);   // 0 on first tile
      l_part *= f;
#pragma unroll
      for (int dj = 0; dj < 4; ++dj)
#pragma unroll
        for (int i = 0; i < 4; ++i) oacc[dj][i] *= f;
      m_run = vm;
    }

    // P = exp2(S - m), packed directly into PV A-fragments (k-slot j <-> nj=2ks+(j>>2), r=j&3)
    FragU pa[2];
    float psum = 0.f;
#pragma unroll
    for (int nj = 0; nj < 4; ++nj)
#pragma unroll
      for (int r = 0; r < 4; ++r) {
        float p = exp2f(s[nj][r] - m_run);
        psum += p;
        BfU cv; cv.h = (__bf16)p;
        pa[nj >> 1].u[(nj & 1) * 4 + r] = cv.u;
      }
    l_part += psum;

    // O += P @ V : B-operand from Vs rows (V^T), kv order matching kappa
    __builtin_amdgcn_s_setprio(1);
#pragma unroll
    for (int ks = 0; ks < 2; ++ks) {
#pragma unroll
      for (int dj = 0; dj < 4; ++dj) {
        const u16* vrow = &Vs[dj*16 + c][ks*32 + 4*g];
        u16x4 lo = *(const u16x4*)vrow;
        u16x4 hi = *(const u16x4*)(vrow + 16);
        FragU vf;
#pragma unroll
        for (int e = 0; e < 4; ++e) { vf.u[e] = lo[e]; vf.u[4+e] = hi[e]; }
        oacc[dj] = __builtin_amdgcn_mfma_f32_16x16x32_bf16(pa[ks].b, vf.b, oacc[dj], 0, 0, 0);
      }
    }
    __builtin_amdgcn_s_setprio(0);
  }

  // end: sum l over the 4 lane-groups (same q), redistribute to output rows, store
  l_part += __shfl_xor(l_part, 16);
  l_part += __shfl_xor(l_part, 32);
  u16* Ob = O + ((size_t)(b*TT) + qw0) * EE + h*DD;
#pragma unroll
  for (int i = 0; i < 4; ++i) {
    float li = __shfl(l_part, 4*g + i);   // lane 4g+i holds c = 4g+i
    float inv = 1.f / li;
    int row = 4*g + i;
#pragma unroll
    for (int dj = 0; dj < 4; ++dj)
      Ob[(size_t)row * EE + dj*16 + c] = f2bf(oacc[dj][i] * inv);
  }
}

// ---------------- launch ----------------
extern "C" void kernel_launch(void* const* d_in, const int* in_sizes, int n_in,
                              void* d_out, int out_size, void* d_ws, size_t ws_size,
                              hipStream_t stream) {
  const float* x  = (const float*)d_in[0];
  const float* y  = (const float*)d_in[1];
  // d_in[2] = mask (tril causal; implemented analytically)
  const float* Wq = (const float*)d_in[3];
  const float* bq = (const float*)d_in[4];
  const float* Wk = (const float*)d_in[5];
  const float* bk = (const float*)d_in[6];
  const float* Wv = (const float*)d_in[7];
  const float* bv = (const float*)d_in[8];
  const float* Wo = (const float*)d_in[9];
  const float* bo = (const float*)d_in[10];

  if (ws_size < (size_t)50331648) return;  // need 48 MiB scratch

  char* ws = (char*)d_ws;
  u16* Wqt  = (u16*)(ws + 0);          // [1024][1024] bf16, 2 MiB
  u16* Wkvt = (u16*)(ws + 2097152);    // [2048][1024] bf16, 4 MiB ([Wk^T | Wv^T] rows)
  u16* Wot  = (u16*)(ws + 6291456);    // [1024][1024] bf16, 2 MiB
  u16* Qb   = (u16*)(ws + 8388608);    // [4096][1024] bf16, 8 MiB
  u16* KVb  = (u16*)(ws + 16777216);   // [4096][2048] bf16, 16 MiB ([K | V] cols)
  u16* Vtb  = (u16*)(ws + 33554432);   // [2][16][64][2048] bf16, 8 MiB
  u16* Atb  = (u16*)(ws + 41943040);   // [4096][1024] bf16, 8 MiB

  const float c1 = 0.125f * 1.44269504088896340736f;  // scale * log2(e), folded into Q

  wt_cvt4<<<dim3(16,16,4), 256, 0, stream>>>(Wq, Wk, Wv, Wo,
                                             Wqt, Wkvt, Wkvt + (size_t)1024*EE, Wot);
  gemm_bt<true,  false><<<dim3(8, 64), 256, 0, stream>>>(x, Wqt, bq, bq, EE, Qb, MM, 1024, EE, c1);
  gemm_bt<true,  false><<<dim3(16,64), 256, 0, stream>>>(y, Wkvt, bk, bv, 1024, KVb, MM, 2048, EE, 1.0f);
  transpose_v<<<dim3(32,16,2), 256, 0, stream>>>(KVb, Vtb);
  attn<<<1024, 256, 0, stream>>>(Qb, KVb, Vtb, Atb);
  gemm_bt<false, true><<<dim3(8, 64), 256, 0, stream>>>(Atb, Wot, bo, bo, EE, d_out, MM, 1024, EE, 1.0f);
}